// Round 9
// baseline (610.846 us; speedup 1.0000x reference)
//
#include <hip/hip_runtime.h>
#include <hip/hip_bf16.h>
#include <stdint.h>

#define N_NODES 100000
#define N_EDGES 3200000
#define N_GRAPHS 64
#define BSH 7        // bucket = 128 nodes
#define NBK 128      // nodes per bucket
#define NB 782       // ceil(100000/128) buckets
#define G_SC 512     // scatter/hist blocks
#define EPB 6250     // edges per scatter block (512*6250 == 3200000 exactly)

typedef unsigned int u32;
typedef unsigned short u16;
typedef __attribute__((ext_vector_type(8))) short bf16x8;
typedef __attribute__((ext_vector_type(4))) float f32x4;

__device__ __forceinline__ float bf_lo(u32 u){ return __uint_as_float(u << 16); }
__device__ __forceinline__ float bf_hi(u32 u){ return __uint_as_float(u & 0xffff0000u); }
__device__ __forceinline__ u16 f2bf(float f){
    union { __hip_bfloat16 h; u16 u; } c; c.h = __float2bfloat16(f); return c.u;
}
__device__ __forceinline__ u32 pack2(float a, float b){
    return (u32)f2bf(a) | ((u32)f2bf(b) << 16);
}

// ---- A1: per-block coarse histogram over NB buckets (dst>>BSH); LDS atomics only ----
__global__ __launch_bounds__(512) void k_hist(const int* __restrict__ dst,
                                              int* __restrict__ hist){
    __shared__ int h[NB];
    int tid = threadIdx.x, g = blockIdx.x;
    for (int i = tid; i < NB; i += 512) h[i] = 0;
    __syncthreads();
    const int2* d2 = reinterpret_cast<const int2*>(dst + g * EPB);
    for (int i = tid; i < EPB / 2; i += 512){
        int2 d = d2[i];
        atomicAdd(&h[d.x >> BSH], 1);
        atomicAdd(&h[d.y >> BSH], 1);
    }
    __syncthreads();
    for (int i = tid; i < NB; i += 512) hist[i * G_SC + g] = h[i];  // bucket-major
}

// ---- A2: per-bucket exclusive scan over blocks -> relative cursors + bucket totals ----
__global__ __launch_bounds__(512) void k_colscan(const int* __restrict__ hist,
                                                 int* __restrict__ cursors,
                                                 int* __restrict__ btot){
    __shared__ int sm[512];
    int b = blockIdx.x, tid = threadIdx.x;
    int v = hist[b * G_SC + tid];
    sm[tid] = v; __syncthreads();
    for (int off = 1; off < 512; off <<= 1){
        int t = (tid >= off) ? sm[tid - off] : 0;
        __syncthreads(); sm[tid] += t; __syncthreads();
    }
    cursors[b * G_SC + tid] = sm[tid] - v;   // relative to bucket base
    if (tid == 511) btot[b] = sm[511];
}

// ---- A2b: exclusive scan of bucket totals -> bucket bases ----
__global__ __launch_bounds__(1024) void k_bscan(const int* __restrict__ btot,
                                                int* __restrict__ bbase){
    __shared__ int sm[1024];
    int tid = threadIdx.x;
    int v = (tid < NB) ? btot[tid] : 0;
    sm[tid] = v; __syncthreads();
    for (int off = 1; off < 1024; off <<= 1){
        int t = (tid >= off) ? sm[tid - off] : 0;
        __syncthreads(); sm[tid] += t; __syncthreads();
    }
    if (tid < NB) bbase[tid] = sm[tid] - v;  // exclusive
    if (tid == 0) bbase[NB] = N_EDGES;
}

// ---- A3: scatter packed (src | dstLow<<24) into coarse buckets ----
__global__ __launch_bounds__(512) void k_scatter(const int* __restrict__ src,
                                                 const int* __restrict__ dst,
                                                 const int* __restrict__ cursors,
                                                 const int* __restrict__ bbase,
                                                 u32* __restrict__ pairs){
    __shared__ int cur[NB];
    int g = blockIdx.x, tid = threadIdx.x;
    for (int i = tid; i < NB; i += 512) cur[i] = cursors[i * G_SC + g] + bbase[i];
    __syncthreads();
    const int2* s2 = reinterpret_cast<const int2*>(src + g * EPB);
    const int2* d2 = reinterpret_cast<const int2*>(dst + g * EPB);
    for (int i = tid; i < EPB / 2; i += 512){
        int2 s = s2[i]; int2 d = d2[i];
        int p0 = atomicAdd(&cur[d.x >> BSH], 1);
        pairs[p0] = (u32)s.x | ((u32)(d.x & (NBK - 1)) << 24);
        int p1 = atomicAdd(&cur[d.y >> BSH], 1);
        pairs[p1] = (u32)s.y | ((u32)(d.y & (NBK - 1)) << 24);
    }
}

// ---- B: fused per-bucket pass: LDS degree count -> dinv + node offsets (LDS scan)
//      -> fine CSR fill. Zero global atomics. ----
__global__ __launch_bounds__(512) void k_fine(const u32* __restrict__ pairs,
                                              const int* __restrict__ bbase,
                                              int* __restrict__ offsets,
                                              float* __restrict__ dinv,
                                              int* __restrict__ csr_src){
    __shared__ int ldeg[NBK];
    __shared__ int ssc[NBK];
    __shared__ int lcur[NBK];
    int b = blockIdx.x, tid = threadIdx.x;
    int node0 = b << BSH;
    if (tid < NBK) ldeg[tid] = 0;
    __syncthreads();
    int e0 = bbase[b], e1 = bbase[b + 1];
    for (int e = e0 + tid; e < e1; e += 512)
        atomicAdd(&ldeg[pairs[e] >> 24], 1);
    __syncthreads();
    int myDeg = (tid < NBK) ? ldeg[tid] : 0;
    if (tid < NBK) ssc[tid] = myDeg;
    __syncthreads();
    for (int off = 1; off < NBK; off <<= 1){
        int t = 0;
        if (tid >= off && tid < NBK) t = ssc[tid - off];
        __syncthreads();
        if (tid < NBK) ssc[tid] += t;
        __syncthreads();
    }
    if (tid < NBK){
        int excl = ssc[tid] - myDeg;
        int n = node0 + tid;
        if (n <= N_NODES) offsets[n] = e0 + excl;   // n==N_NODES lands on e1==N_EDGES
        if (n < N_NODES)  dinv[n] = rsqrtf((float)myDeg + 1.0f);  // +1 self loop
        lcur[tid] = e0 + excl;
    }
    __syncthreads();
    for (int e = e0 + tid; e < e1; e += 512){
        u32 p = pairs[e];
        int pos = atomicAdd(&lcur[p >> 24], 1);
        csr_src[pos] = (int)(p & 0xFFFFFFu);
    }
}

// ---- f32 -> bf16 row-major [N][128], dinv[row] folded in; 4 floats/thread ----
__global__ void k_cvt_x(const float* __restrict__ x, const float* __restrict__ dinv,
                        u32* __restrict__ xb){
    int i = blockIdx.x * blockDim.x + threadIdx.x;  // [0, N*32)
    if (i < N_NODES * 32){
        float w = dinv[i >> 5];
        float4 f = reinterpret_cast<const float4*>(x)[i];
        uint2 p = make_uint2(pack2(f.x * w, f.y * w), pack2(f.z * w, f.w * w));
        reinterpret_cast<uint2*>(xb)[i] = p;
    }
}

// ---- both weight transposes in one launch: W[K][N] f32 -> WT[N][K] bf16 ----
__global__ void k_cvt_w(const float* __restrict__ W1, const float* __restrict__ W2,
                        u16* __restrict__ w1t, u16* __restrict__ w2t){
    int i = blockIdx.x * blockDim.x + threadIdx.x;
    if (i < 128 * 256){           // W1: K=128, N=256
        int n = i / 128, k = i % 128;
        w1t[i] = f2bf(W1[k * 256 + n]);
    } else {                      // W2: K=256, N=128
        int j = i - 128 * 256;
        int n = j / 256, k = j % 256;
        w2t[j] = f2bf(W2[k * 128 + n]);
    }
}

// ---- edge aggregation (full 256B rows): out[v] = dinv[v]*(X'[v] + sum X'[src])
// X' bf16 [N][128] prescaled, packed u32 pairs. One wave per node, 2 ch/lane.
// 8 independent row-gathers in flight per inner iteration. bf16 out.
__global__ __launch_bounds__(256) void k_agg(const u32* __restrict__ X,
                      const int* __restrict__ offs, const int* __restrict__ csr_src,
                      const float* __restrict__ dinv, u32* __restrict__ out){
    int lane = threadIdx.x & 63;
    int v = blockIdx.x * 4 + (threadIdx.x >> 6);
    u32 u = X[v * 64 + lane];
    float a0 = bf_lo(u), a1 = bf_hi(u);
    int e1 = offs[v + 1];
    for (int e = offs[v]; e < e1; e += 64){
        int idx = e + lane;
        int sv = (idx < e1) ? csr_src[idx] : 0;
        int cnt = min(64, e1 - e);
        int j = 0;
        for (; j + 8 <= cnt; j += 8){
            int s0 = __shfl(sv, j),   s1 = __shfl(sv, j+1), s2 = __shfl(sv, j+2), s3 = __shfl(sv, j+3);
            int s4 = __shfl(sv, j+4), s5 = __shfl(sv, j+5), s6 = __shfl(sv, j+6), s7 = __shfl(sv, j+7);
            u32 u0 = X[s0*64 + lane], u1 = X[s1*64 + lane], u2 = X[s2*64 + lane], u3 = X[s3*64 + lane];
            u32 u4 = X[s4*64 + lane], u5 = X[s5*64 + lane], u6 = X[s6*64 + lane], u7 = X[s7*64 + lane];
            a0 += (bf_lo(u0) + bf_lo(u1)) + (bf_lo(u2) + bf_lo(u3))
                + (bf_lo(u4) + bf_lo(u5)) + (bf_lo(u6) + bf_lo(u7));
            a1 += (bf_hi(u0) + bf_hi(u1)) + (bf_hi(u2) + bf_hi(u3))
                + (bf_hi(u4) + bf_hi(u5)) + (bf_hi(u6) + bf_hi(u7));
        }
        for (; j < cnt; j++){
            int s = __shfl(sv, j);
            u32 uu = X[s*64 + lane];
            a0 += bf_lo(uu); a1 += bf_hi(uu);
        }
    }
    float w = dinv[v];
    out[v*64 + lane] = pack2(a0 * w, a1 * w);
}

// ---- bf16 MFMA GEMM: C[M][BN] = A[M][BK] @ BT[BN][BK]^T (+bias)(+relu)(*rowscale)
// A staged in static LDS (XOR-swizzled); B (tiny, L2-hot weights) read from global.
template<int BK, int BN, bool RELU, bool BIAS, bool SCALE>
__global__ __launch_bounds__(256) void k_gemm(const u16* __restrict__ A, const u16* __restrict__ BT,
                        const float* __restrict__ bias, const float* __restrict__ rowscale,
                        u16* __restrict__ C, int M){
    __shared__ char As[64 * BK * 2];
    const int tid = threadIdx.x;
    const int rowbytes = BK * 2;
    const int units = 8 * BK;   // 64*rowbytes/16
    for (int it = tid; it < units; it += 256){
        int flat = it * 16;
        int r = flat / rowbytes, cb = flat % rowbytes;
        int grow = blockIdx.x * 64 + r;
        int4 val = make_int4(0,0,0,0);
        if (grow < M) val = *reinterpret_cast<const int4*>(A + (size_t)grow * BK + cb / 2);
        *reinterpret_cast<int4*>(As + r * rowbytes + (cb ^ ((r & 7) << 4))) = val;
    }
    __syncthreads();

    const int wid = tid >> 6, lane = tid & 63;
    const int r0 = wid * 16;
    constexpr int NF = BN / 16;
    f32x4 acc[NF];
#pragma unroll
    for (int i = 0; i < NF; i++) acc[i] = (f32x4){0.f,0.f,0.f,0.f};
    const int ar = r0 + (lane & 15);
    const int koff = (lane >> 4) * 8;   // element offset within k-slice
#pragma unroll
    for (int kb = 0; kb < BK / 32; kb++){
        int kbyte = (kb * 32 + koff) * 2;
        bf16x8 aF = *reinterpret_cast<const bf16x8*>(As + ar * rowbytes + (kbyte ^ ((ar & 7) << 4)));
#pragma unroll
        for (int nf = 0; nf < NF; nf++){
            int bn = nf * 16 + (lane & 15);
            bf16x8 bF = *reinterpret_cast<const bf16x8*>(BT + bn * BK + kb * 32 + koff);
            acc[nf] = __builtin_amdgcn_mfma_f32_16x16x32_bf16(aF, bF, acc[nf], 0, 0, 0);
        }
    }
#pragma unroll
    for (int nf = 0; nf < NF; nf++){
        int col = nf * 16 + (lane & 15);
        float bv = BIAS ? bias[col] : 0.f;
#pragma unroll
        for (int j = 0; j < 4; j++){
            int grow = blockIdx.x * 64 + r0 + (lane >> 4) * 4 + j;
            if (grow < M){
                float val = acc[nf][j] + bv;
                if (RELU) val = fmaxf(val, 0.f);
                if (SCALE) val *= rowscale[grow];
                C[(size_t)grow * BN + col] = f2bf(val);
            }
        }
    }
}

// ---- pool over row-major bf16 [N][128] (u32 pairs): batch sorted; run-accumulate ----
// 64 threads/block, each owns one u32 column (2 channels).
__global__ void k_pool(const u32* __restrict__ t2, const int* __restrict__ batch,
                       float* __restrict__ psum, float* __restrict__ counts){
    const int NPB = 100;  // grid=1000
    int n0 = blockIdx.x * NPB, n1 = min(n0 + NPB, N_NODES);
    int tid = threadIdx.x;  // u32 col 0..63
    float r0 = 0.f, r1 = 0.f; int gcur = batch[n0]; int runlen = 0;
    for (int n = n0; n < n1; n++){
        int g = batch[n];
        if (g != gcur){
            atomicAdd(&psum[gcur * 128 + 2 * tid], r0);
            atomicAdd(&psum[gcur * 128 + 2 * tid + 1], r1);
            if (tid == 0) atomicAdd(&counts[gcur], (float)runlen);
            r0 = 0.f; r1 = 0.f; runlen = 0; gcur = g;
        }
        u32 u = t2[(size_t)n * 64 + tid];
        r0 += bf_lo(u); r1 += bf_hi(u);
        runlen++;
    }
    atomicAdd(&psum[gcur * 128 + 2 * tid], r0);
    atomicAdd(&psum[gcur * 128 + 2 * tid + 1], r1);
    if (tid == 0) atomicAdd(&counts[gcur], (float)runlen);
}

__global__ void k_final(const float* __restrict__ psum, const float* __restrict__ counts,
                        const float* __restrict__ b2, float* __restrict__ out){
    int g = blockIdx.x, c = threadIdx.x;
    out[g * 128 + c] = psum[g * 128 + c] / fmaxf(counts[g], 1.0f) + b2[c];
}

extern "C" void kernel_launch(void* const* d_in, const int* in_sizes, int n_in,
                              void* d_out, int out_size, void* d_ws, size_t ws_size,
                              hipStream_t stream){
    const float* x   = (const float*)d_in[0];
    const int*   ei  = (const int*)d_in[1];
    const int* batch = (const int*)d_in[2];
    const float* W1  = (const float*)d_in[3];
    const float* b1  = (const float*)d_in[4];
    const float* W2  = (const float*)d_in[5];
    const float* b2  = (const float*)d_in[6];
    float* out = (float*)d_out;
    const int* esrc = ei;
    const int* edst = ei + N_EDGES;

    char* w = (char*)d_ws;
    size_t off = 0;
    auto alloc = [&](size_t bytes) -> char* {
        char* p = w + off; off += (bytes + 255) & ~size_t(255); return p;
    };
    float* dinv     = (float*)alloc((size_t)N_NODES * 4);
    int*   offsets  = (int*)  alloc((size_t)(N_NODES + 1) * 4);
    int*   hist     = (int*)  alloc((size_t)NB * G_SC * 4);
    int*   cursors  = (int*)  alloc((size_t)NB * G_SC * 4);
    int*   btot     = (int*)  alloc((size_t)NB * 4);
    int*   bbase    = (int*)  alloc((size_t)(NB + 1) * 4);
    int*   csr_src  = (int*)  alloc((size_t)N_EDGES * 4);
    u32*   xb       = (u32*)  alloc((size_t)N_NODES * 64 * 4);   // bf16 [N][128] prescaled
    u16*   aggx     = (u16*)  alloc((size_t)N_NODES * 128 * 2);  // bf16 [N][128]
    u16*   h        = (u16*)  alloc((size_t)N_NODES * 256 * 2);  // bf16 [N][256]
    u16*   t        = (u16*)  alloc((size_t)N_NODES * 128 * 2);  // bf16 [N][128] prescaled
    u16*   w1t      = (u16*)  alloc(128 * 256 * 2);
    u16*   w2t      = (u16*)  alloc(256 * 128 * 2);
    float* psum     = (float*)alloc((size_t)N_GRAPHS * 128 * 4);
    float* counts   = (float*)alloc((size_t)N_GRAPHS * 4);
    u32*   t2       = (u32*)h;     // alias: h dead after gemm2; bf16 [N][128] agg2 out
    u32*   pairs    = (u32*)h;     // alias: h unwritten during CSR build (12.8MB < 51.2MB)

    hipMemsetAsync(psum, 0, (size_t)N_GRAPHS * 128 * 4, stream);
    hipMemsetAsync(counts, 0, (size_t)N_GRAPHS * 4, stream);

    // counting-sort CSR build; degrees/dinv/offsets all derived bucket-locally
    k_hist   <<<G_SC, 512, 0, stream>>>(edst, hist);
    k_colscan<<<NB, 512, 0, stream>>>(hist, cursors, btot);
    k_bscan  <<<1, 1024, 0, stream>>>(btot, bbase);
    k_scatter<<<G_SC, 512, 0, stream>>>(esrc, edst, cursors, bbase, pairs);
    k_fine   <<<NB, 512, 0, stream>>>(pairs, bbase, offsets, dinv, csr_src);

    k_cvt_x<<<12500, 256, 0, stream>>>(x, dinv, xb);
    k_cvt_w<<<256, 256, 0, stream>>>(W1, W2, w1t, w2t);

    // layer 1: aggx = dinv*(gather-sum of prescaled x) (bf16), h = relu(aggx@W1+b1)
    k_agg<<<25000, 256, 0, stream>>>(xb, offsets, csr_src, dinv, (u32*)aggx);
    k_gemm<128, 256, true, true, false><<<1563, 256, 0, stream>>>(
        aggx, w1t, b1, nullptr, h, N_NODES);
    // layer 2: t = (h@W2)*dinv[row] (bf16, prescaled), t2 = dinv*(gather-sum of t) (bf16)
    k_gemm<256, 128, false, false, true><<<1563, 256, 0, stream>>>(
        h, w2t, nullptr, dinv, t, N_NODES);
    k_agg<<<25000, 256, 0, stream>>>((const u32*)t, offsets, csr_src, dinv, t2);
    k_pool <<<1000, 64, 0, stream>>>(t2, batch, psum, counts);
    k_final<<<N_GRAPHS, 128, 0, stream>>>(psum, counts, b2, out);
}

// Round 11
// 547.615 us; speedup vs baseline: 1.1155x; 1.1155x over previous
//
#include <hip/hip_runtime.h>
#include <hip/hip_bf16.h>
#include <stdint.h>

#define N_NODES 100000
#define N_EDGES 3200000
#define N_GRAPHS 64
#define BSH 8        // bucket = 256 nodes (64B avg scatter region per block — full line)
#define NBK 256      // nodes per bucket
#define NB 391       // ceil(100000/256) buckets
#define G_SC 512     // scatter/hist blocks
#define EPB 6250     // edges per scatter block (512*6250 == 3200000 exactly)

typedef unsigned int u32;
typedef unsigned short u16;
typedef __attribute__((ext_vector_type(8))) short bf16x8;
typedef __attribute__((ext_vector_type(4))) float f32x4;

__device__ __forceinline__ float bf_lo(u32 u){ return __uint_as_float(u << 16); }
__device__ __forceinline__ float bf_hi(u32 u){ return __uint_as_float(u & 0xffff0000u); }
__device__ __forceinline__ u16 f2bf(float f){
    union { __hip_bfloat16 h; u16 u; } c; c.h = __float2bfloat16(f); return c.u;
}
__device__ __forceinline__ u32 pack2(float a, float b){
    return (u32)f2bf(a) | ((u32)f2bf(b) << 16);
}

// ---- A1: per-block coarse histogram over NB buckets; also zeros psum/counts ----
__global__ __launch_bounds__(512) void k_hist(const int* __restrict__ dst,
                                              int* __restrict__ hist,
                                              float* __restrict__ psum,
                                              float* __restrict__ counts){
    __shared__ int h[NB];
    int tid = threadIdx.x, g = blockIdx.x;
    if (g == 0){
        for (int i = tid; i < N_GRAPHS * 128; i += 512) psum[i] = 0.f;
        if (tid < N_GRAPHS) counts[tid] = 0.f;
    }
    for (int i = tid; i < NB; i += 512) h[i] = 0;
    __syncthreads();
    const int2* d2 = reinterpret_cast<const int2*>(dst + g * EPB);
    for (int i = tid; i < EPB / 2; i += 512){
        int2 d = d2[i];
        atomicAdd(&h[d.x >> BSH], 1);
        atomicAdd(&h[d.y >> BSH], 1);
    }
    __syncthreads();
    for (int i = tid; i < NB; i += 512) hist[i * G_SC + g] = h[i];  // bucket-major
}

// ---- A2: per-bucket exclusive scan over blocks -> relative cursors + bucket totals ----
__global__ __launch_bounds__(512) void k_colscan(const int* __restrict__ hist,
                                                 int* __restrict__ cursors,
                                                 int* __restrict__ btot){
    __shared__ int sm[512];
    int b = blockIdx.x, tid = threadIdx.x;
    int v = hist[b * G_SC + tid];
    sm[tid] = v; __syncthreads();
    for (int off = 1; off < 512; off <<= 1){
        int t = (tid >= off) ? sm[tid - off] : 0;
        __syncthreads(); sm[tid] += t; __syncthreads();
    }
    cursors[b * G_SC + tid] = sm[tid] - v;   // relative to bucket base
    if (tid == 511) btot[b] = sm[511];
}

// ---- A2b: exclusive scan of bucket totals -> bucket bases ----
__global__ __launch_bounds__(512) void k_bscan(const int* __restrict__ btot,
                                               int* __restrict__ bbase){
    __shared__ int sm[512];
    int tid = threadIdx.x;
    int v = (tid < NB) ? btot[tid] : 0;
    sm[tid] = v; __syncthreads();
    for (int off = 1; off < 512; off <<= 1){
        int t = (tid >= off) ? sm[tid - off] : 0;
        __syncthreads(); sm[tid] += t; __syncthreads();
    }
    if (tid < NB) bbase[tid] = sm[tid] - v;  // exclusive
    if (tid == 0) bbase[NB] = N_EDGES;
}

// ---- A3: scatter packed (src | dstLow<<24) into coarse buckets ----
__global__ __launch_bounds__(512) void k_scatter(const int* __restrict__ src,
                                                 const int* __restrict__ dst,
                                                 const int* __restrict__ cursors,
                                                 const int* __restrict__ bbase,
                                                 u32* __restrict__ pairs){
    __shared__ int cur[NB];
    int g = blockIdx.x, tid = threadIdx.x;
    for (int i = tid; i < NB; i += 512) cur[i] = cursors[i * G_SC + g] + bbase[i];
    __syncthreads();
    const int2* s2 = reinterpret_cast<const int2*>(src + g * EPB);
    const int2* d2 = reinterpret_cast<const int2*>(dst + g * EPB);
    for (int i = tid; i < EPB / 2; i += 512){
        int2 s = s2[i]; int2 d = d2[i];
        int p0 = atomicAdd(&cur[d.x >> BSH], 1);
        pairs[p0] = (u32)s.x | ((u32)(d.x & (NBK - 1)) << 24);
        int p1 = atomicAdd(&cur[d.y >> BSH], 1);
        pairs[p1] = (u32)s.y | ((u32)(d.y & (NBK - 1)) << 24);
    }
}

// ---- B: fused per-bucket pass: LDS degree count -> dinv + node offsets (LDS scan)
//      -> fine CSR fill. Zero global atomics. ----
__global__ __launch_bounds__(512) void k_fine(const u32* __restrict__ pairs,
                                              const int* __restrict__ bbase,
                                              int* __restrict__ offsets,
                                              float* __restrict__ dinv,
                                              int* __restrict__ csr_src){
    __shared__ int ldeg[NBK];
    __shared__ int ssc[NBK];
    __shared__ int lcur[NBK];
    int b = blockIdx.x, tid = threadIdx.x;
    int node0 = b << BSH;
    if (tid < NBK) ldeg[tid] = 0;
    __syncthreads();
    int e0 = bbase[b], e1 = bbase[b + 1];
    for (int e = e0 + tid; e < e1; e += 512)
        atomicAdd(&ldeg[pairs[e] >> 24], 1);
    __syncthreads();
    int myDeg = (tid < NBK) ? ldeg[tid] : 0;
    if (tid < NBK) ssc[tid] = myDeg;
    __syncthreads();
    for (int off = 1; off < NBK; off <<= 1){
        int t = 0;
        if (tid >= off && tid < NBK) t = ssc[tid - off];
        __syncthreads();
        if (tid < NBK) ssc[tid] += t;
        __syncthreads();
    }
    if (tid < NBK){
        int excl = ssc[tid] - myDeg;
        int n = node0 + tid;
        if (n <= N_NODES) offsets[n] = e0 + excl;   // n==N_NODES lands on e1==N_EDGES
        if (n < N_NODES)  dinv[n] = rsqrtf((float)myDeg + 1.0f);  // +1 self loop
        lcur[tid] = e0 + excl;
    }
    __syncthreads();
    for (int e = e0 + tid; e < e1; e += 512){
        u32 p = pairs[e];
        int pos = atomicAdd(&lcur[p >> 24], 1);
        csr_src[pos] = (int)(p & 0xFFFFFFu);
    }
}

// ---- prep: f32->bf16 x (dinv folded) + both weight transposes, one launch ----
// blocks [0,12500): x; blocks [12500,12756): weights
__global__ void k_prep(const float* __restrict__ x, const float* __restrict__ dinv,
                       u32* __restrict__ xb,
                       const float* __restrict__ W1, const float* __restrict__ W2,
                       u16* __restrict__ w1t, u16* __restrict__ w2t){
    int bid = blockIdx.x;
    if (bid < 12500){
        int i = bid * 256 + threadIdx.x;   // [0, N*32) exactly
        float w = dinv[i >> 5];
        float4 f = reinterpret_cast<const float4*>(x)[i];
        uint2 p = make_uint2(pack2(f.x * w, f.y * w), pack2(f.z * w, f.w * w));
        reinterpret_cast<uint2*>(xb)[i] = p;
    } else {
        int i = (bid - 12500) * 256 + threadIdx.x;
        if (i < 128 * 256){           // W1: K=128, N=256
            int n = i / 128, k = i % 128;
            w1t[i] = f2bf(W1[k * 256 + n]);
        } else {                      // W2: K=256, N=128
            int j = i - 128 * 256;
            int n = j / 256, k = j % 256;
            w2t[j] = f2bf(W2[k * 128 + n]);
        }
    }
}

// ---- edge aggregation (full 256B rows): out[v] = dinv[v]*(X'[v] + sum X'[src])
// X' bf16 [N][128] prescaled, packed u32 pairs. One wave per node, 2 ch/lane.
// 8 independent row-gathers in flight per inner iteration. bf16 out.
__global__ __launch_bounds__(256) void k_agg(const u32* __restrict__ X,
                      const int* __restrict__ offs, const int* __restrict__ csr_src,
                      const float* __restrict__ dinv, u32* __restrict__ out){
    int lane = threadIdx.x & 63;
    int v = blockIdx.x * 4 + (threadIdx.x >> 6);
    u32 u = X[v * 64 + lane];
    float a0 = bf_lo(u), a1 = bf_hi(u);
    int e1 = offs[v + 1];
    for (int e = offs[v]; e < e1; e += 64){
        int idx = e + lane;
        int sv = (idx < e1) ? csr_src[idx] : 0;
        int cnt = min(64, e1 - e);
        int j = 0;
        for (; j + 8 <= cnt; j += 8){
            int s0 = __shfl(sv, j),   s1 = __shfl(sv, j+1), s2 = __shfl(sv, j+2), s3 = __shfl(sv, j+3);
            int s4 = __shfl(sv, j+4), s5 = __shfl(sv, j+5), s6 = __shfl(sv, j+6), s7 = __shfl(sv, j+7);
            u32 u0 = X[s0*64 + lane], u1 = X[s1*64 + lane], u2 = X[s2*64 + lane], u3 = X[s3*64 + lane];
            u32 u4 = X[s4*64 + lane], u5 = X[s5*64 + lane], u6 = X[s6*64 + lane], u7 = X[s7*64 + lane];
            a0 += (bf_lo(u0) + bf_lo(u1)) + (bf_lo(u2) + bf_lo(u3))
                + (bf_lo(u4) + bf_lo(u5)) + (bf_lo(u6) + bf_lo(u7));
            a1 += (bf_hi(u0) + bf_hi(u1)) + (bf_hi(u2) + bf_hi(u3))
                + (bf_hi(u4) + bf_hi(u5)) + (bf_hi(u6) + bf_hi(u7));
        }
        for (; j < cnt; j++){
            int s = __shfl(sv, j);
            u32 uu = X[s*64 + lane];
            a0 += bf_lo(uu); a1 += bf_hi(uu);
        }
    }
    float w = dinv[v];
    out[v*64 + lane] = pack2(a0 * w, a1 * w);
}

// ---- fused 2-layer MLP: t = (relu(aggx@W1 + b1) @ W2) * dinv[row], bf16 out.
// Per block: 64 rows. Intermediate 64x256 bf16 kept in LDS (XOR-swizzled, same
// precision as the old global round-trip). B operands read from global (L2-hot).
__global__ __launch_bounds__(256) void k_mlp(const u16* __restrict__ A,
                        const u16* __restrict__ B1T, const u16* __restrict__ B2T,
                        const float* __restrict__ b1, const float* __restrict__ dinv,
                        u16* __restrict__ C, int M){
    __shared__ char As[64 * 256];   // 64 x 128 bf16, swizzled (16KB)
    __shared__ char C1[64 * 512];   // 64 x 256 bf16, swizzled (32KB)
    const int tid = threadIdx.x;
    // stage A tile (rowbytes 256)
    for (int it = tid; it < 1024; it += 256){
        int flat = it * 16;
        int r = flat >> 8, cb = flat & 255;
        int grow = blockIdx.x * 64 + r;
        int4 val = make_int4(0,0,0,0);
        if (grow < M) val = *reinterpret_cast<const int4*>(A + (size_t)grow * 128 + cb / 2);
        *reinterpret_cast<int4*>(As + r * 256 + (cb ^ ((r & 7) << 4))) = val;
    }
    __syncthreads();

    const int wid = tid >> 6, lane = tid & 63;
    const int r0 = wid * 16;
    const int ar = r0 + (lane & 15);
    const int koff = (lane >> 4) * 8;
    // ---- stage 1: C1 = relu(A@W1 + b1), 64x256 ----
    {
        f32x4 acc[16];
#pragma unroll
        for (int i = 0; i < 16; i++) acc[i] = (f32x4){0.f,0.f,0.f,0.f};
#pragma unroll
        for (int kb = 0; kb < 4; kb++){
            int kbyte = (kb * 32 + koff) * 2;
            bf16x8 aF = *reinterpret_cast<const bf16x8*>(As + ar * 256 + (kbyte ^ ((ar & 7) << 4)));
#pragma unroll
            for (int nf = 0; nf < 16; nf++){
                int bn = nf * 16 + (lane & 15);
                bf16x8 bF = *reinterpret_cast<const bf16x8*>(B1T + bn * 128 + kb * 32 + koff);
                acc[nf] = __builtin_amdgcn_mfma_f32_16x16x32_bf16(aF, bF, acc[nf], 0, 0, 0);
            }
        }
#pragma unroll
        for (int nf = 0; nf < 16; nf++){
            int col = nf * 16 + (lane & 15);
            float bv = b1[col];
#pragma unroll
            for (int j = 0; j < 4; j++){
                int r = r0 + (lane >> 4) * 4 + j;
                float val = fmaxf(acc[nf][j] + bv, 0.f);
                *reinterpret_cast<u16*>(C1 + r * 512 + ((col * 2) ^ ((r & 7) << 4))) = f2bf(val);
            }
        }
    }
    __syncthreads();
    // ---- stage 2: t = (C1 @ W2) * dinv, 64x128 ----
    {
        f32x4 acc[8];
#pragma unroll
        for (int i = 0; i < 8; i++) acc[i] = (f32x4){0.f,0.f,0.f,0.f};
#pragma unroll
        for (int kb = 0; kb < 8; kb++){
            int kbyte = (kb * 32 + koff) * 2;
            bf16x8 aF = *reinterpret_cast<const bf16x8*>(C1 + ar * 512 + (kbyte ^ ((ar & 7) << 4)));
#pragma unroll
            for (int nf = 0; nf < 8; nf++){
                int bn = nf * 16 + (lane & 15);
                bf16x8 bF = *reinterpret_cast<const bf16x8*>(B2T + bn * 256 + kb * 32 + koff);
                acc[nf] = __builtin_amdgcn_mfma_f32_16x16x32_bf16(aF, bF, acc[nf], 0, 0, 0);
            }
        }
        float dj[4]; int gr[4];
#pragma unroll
        for (int j = 0; j < 4; j++){
            gr[j] = blockIdx.x * 64 + r0 + (lane >> 4) * 4 + j;
            dj[j] = (gr[j] < M) ? dinv[gr[j]] : 0.f;
        }
#pragma unroll
        for (int nf = 0; nf < 8; nf++){
            int col = nf * 16 + (lane & 15);
#pragma unroll
            for (int j = 0; j < 4; j++){
                if (gr[j] < M) C[(size_t)gr[j] * 128 + col] = f2bf(acc[nf][j] * dj[j]);
            }
        }
    }
}

// ---- pool over row-major bf16 [N][128] (u32 pairs): batch sorted; run-accumulate ----
__global__ void k_pool(const u32* __restrict__ t2, const int* __restrict__ batch,
                       float* __restrict__ psum, float* __restrict__ counts){
    const int NPB = 100;  // grid=1000
    int n0 = blockIdx.x * NPB, n1 = min(n0 + NPB, N_NODES);
    int tid = threadIdx.x;  // u32 col 0..63
    float r0 = 0.f, r1 = 0.f; int gcur = batch[n0]; int runlen = 0;
    for (int n = n0; n < n1; n++){
        int g = batch[n];
        if (g != gcur){
            atomicAdd(&psum[gcur * 128 + 2 * tid], r0);
            atomicAdd(&psum[gcur * 128 + 2 * tid + 1], r1);
            if (tid == 0) atomicAdd(&counts[gcur], (float)runlen);
            r0 = 0.f; r1 = 0.f; runlen = 0; gcur = g;
        }
        u32 u = t2[(size_t)n * 64 + tid];
        r0 += bf_lo(u); r1 += bf_hi(u);
        runlen++;
    }
    atomicAdd(&psum[gcur * 128 + 2 * tid], r0);
    atomicAdd(&psum[gcur * 128 + 2 * tid + 1], r1);
    if (tid == 0) atomicAdd(&counts[gcur], (float)runlen);
}

__global__ void k_final(const float* __restrict__ psum, const float* __restrict__ counts,
                        const float* __restrict__ b2, float* __restrict__ out){
    int g = blockIdx.x, c = threadIdx.x;
    out[g * 128 + c] = psum[g * 128 + c] / fmaxf(counts[g], 1.0f) + b2[c];
}

extern "C" void kernel_launch(void* const* d_in, const int* in_sizes, int n_in,
                              void* d_out, int out_size, void* d_ws, size_t ws_size,
                              hipStream_t stream){
    const float* x   = (const float*)d_in[0];
    const int*   ei  = (const int*)d_in[1];
    const int* batch = (const int*)d_in[2];
    const float* W1  = (const float*)d_in[3];
    const float* b1  = (const float*)d_in[4];
    const float* W2  = (const float*)d_in[5];
    const float* b2  = (const float*)d_in[6];
    float* out = (float*)d_out;
    const int* esrc = ei;
    const int* edst = ei + N_EDGES;

    char* w = (char*)d_ws;
    size_t off = 0;
    auto alloc = [&](size_t bytes) -> char* {
        char* p = w + off; off += (bytes + 255) & ~size_t(255); return p;
    };
    float* dinv     = (float*)alloc((size_t)N_NODES * 4);
    int*   offsets  = (int*)  alloc((size_t)(N_NODES + 1) * 4);
    int*   hist     = (int*)  alloc((size_t)NB * G_SC * 4);
    int*   cursors  = (int*)  alloc((size_t)NB * G_SC * 4);
    int*   btot     = (int*)  alloc((size_t)NB * 4);
    int*   bbase    = (int*)  alloc((size_t)(NB + 1) * 4);
    int*   csr_src  = (int*)  alloc((size_t)N_EDGES * 4);
    u32*   pairs    = (u32*)  alloc((size_t)N_EDGES * 4);
    u32*   xb       = (u32*)  alloc((size_t)N_NODES * 64 * 4);   // bf16 [N][128] prescaled
    u16*   aggx     = (u16*)  alloc((size_t)N_NODES * 128 * 2);  // bf16 [N][128]
    u16*   t        = (u16*)  alloc((size_t)N_NODES * 128 * 2);  // bf16 [N][128] prescaled
    u32*   t2       = (u32*)  alloc((size_t)N_NODES * 64 * 4);   // bf16 [N][128] agg2 out
    u16*   w1t      = (u16*)  alloc(128 * 256 * 2);
    u16*   w2t      = (u16*)  alloc(256 * 128 * 2);
    float* psum     = (float*)alloc((size_t)N_GRAPHS * 128 * 4);
    float* counts   = (float*)alloc((size_t)N_GRAPHS * 4);

    // counting-sort CSR build; degrees/dinv/offsets all derived bucket-locally
    k_hist   <<<G_SC, 512, 0, stream>>>(edst, hist, psum, counts);
    k_colscan<<<NB, 512, 0, stream>>>(hist, cursors, btot);
    k_bscan  <<<1, 512, 0, stream>>>(btot, bbase);
    k_scatter<<<G_SC, 512, 0, stream>>>(esrc, edst, cursors, bbase, pairs);
    k_fine   <<<NB, 512, 0, stream>>>(pairs, bbase, offsets, dinv, csr_src);

    k_prep<<<12756, 256, 0, stream>>>(x, dinv, xb, W1, W2, w1t, w2t);

    // layer 1 agg + fused MLP + layer 2 agg
    k_agg<<<25000, 256, 0, stream>>>(xb, offsets, csr_src, dinv, (u32*)aggx);
    k_mlp<<<1563, 256, 0, stream>>>(aggx, w1t, w2t, b1, dinv, t, N_NODES);
    k_agg<<<25000, 256, 0, stream>>>((const u32*)t, offsets, csr_src, dinv, t2);
    k_pool <<<1000, 64, 0, stream>>>(t2, batch, psum, counts);
    k_final<<<N_GRAPHS, 128, 0, stream>>>(psum, counts, b2, out);
}